// Round 4
// baseline (347.107 us; speedup 1.0000x reference)
//
#include <hip/hip_runtime.h>

#define Bv 8
#define Cv 64
#define Lv 65536
#define TPB 256
#define LOC_PER_BLK 256               // 32 clusters * 2 halves * 4 locations
#define BLKS_PER_B (Lv / LOC_PER_BLK) // 256
#define GRID1 (Bv * BLKS_PER_B)       // 2048
#define L4 (Lv / 4)                   // 16384 float4s per channel row

// workspace budget: partials 2*2048 floats (16 KiB) + sb 1024 floats (4 KiB)
// = 20 KiB total — same proven footprint as R2. Do not grow.

__device__ __forceinline__ void fma_bcast(float w, const float4& v, float4& P) {
    P.x = fmaf(w, v.x, P.x);
    P.y = fmaf(w, v.y, P.y);
    P.z = fmaf(w, v.z, P.z);
    P.w = fmaf(w, v.w, P.w);
}

__device__ __forceinline__ void oct_reduce(float4& P) {
    // reduce across 8-lane cluster (xor 1,2,4)
    P.x += __shfl_xor(P.x, 1); P.y += __shfl_xor(P.y, 1);
    P.z += __shfl_xor(P.z, 1); P.w += __shfl_xor(P.w, 1);
    P.x += __shfl_xor(P.x, 2); P.y += __shfl_xor(P.y, 2);
    P.z += __shfl_xor(P.z, 2); P.w += __shfl_xor(P.w, 2);
    P.x += __shfl_xor(P.x, 4); P.y += __shfl_xor(P.y, 4);
    P.z += __shfl_xor(P.z, 4); P.w += __shfl_xor(P.w, 4);
}

// ---------------------------------------------------------------------------
// Pass 1: 8-lane-cluster fused gate + fuse conv + residual + ReLU.
// Cluster of 8 lanes owns one float4 column at a time (4 locations); each
// lane owns 8 channels -> 64 floats of persistent state. Each cluster
// processes TWO columns sequentially (h=0,1) to amortize LDS weights and
// halve the stats-partial count. launch_bounds(256,4): 4 blocks/CU.
// ---------------------------------------------------------------------------
__global__ __launch_bounds__(TPB, 4)
void pass1(const float* __restrict__ x, const float* __restrict__ inj0,
           const float* __restrict__ inj1, const float* __restrict__ resid,
           const float* __restrict__ gate_w, const float* __restrict__ gate_b,
           const float* __restrict__ fuse_w, const float* __restrict__ fuse_b,
           float* __restrict__ out, float* __restrict__ partials)
{
    __shared__ float gw[Cv * Cv];   // [o][c] row-major (as input)
    __shared__ float fwT[Cv * Cv];  // [o][c] = fuse_w[c][o]
    __shared__ float gb2[Cv], fb[Cv];
    __shared__ float r1[TPB], r2[TPB];

    const int tid = threadIdx.x;
    for (int i = tid; i < Cv * Cv; i += TPB) {
        gw[i]  = gate_w[i];
        fwT[i] = fuse_w[((i & 63) << 6) | (i >> 6)];
    }
    if (tid < Cv) { gb2[tid] = 2.0f * gate_b[tid]; fb[tid] = fuse_b[tid]; }
    __syncthreads();

    const int g  = tid & 7;    // member within cluster: owns 8 channels
    const int q  = tid >> 3;   // cluster id within block (0..31)
    const int c0 = g << 3;     // first owned channel

    const int b    = blockIdx.x >> 8;        // / BLKS_PER_B
    const int lb   = blockIdx.x & 255;       // % BLKS_PER_B
    const int base4 = ((b * Cv * Lv) >> 2) + ((lb * LOC_PER_BLK) >> 2);

    const float4* x4  = reinterpret_cast<const float4*>(x);
    const float4* i04 = reinterpret_cast<const float4*>(inj0);
    const float4* i14 = reinterpret_cast<const float4*>(inj1);
    const float4* rs4 = reinterpret_cast<const float4*>(resid);
    float4*       o4  = reinterpret_cast<float4*>(out);

    float lsum = 0.0f, lsq = 0.0f;

    #pragma unroll 1
    for (int h = 0; h < 2; ++h) {
        const int b4 = base4 + (h << 5) + q;   // this cluster's float4 column

        float4 s[8], t[8];
        #pragma unroll
        for (int j = 0; j < 8; ++j) {
            const int i4 = b4 + (c0 + j) * L4;
            const float4 a  = i04[i4];
            const float4 bb = i14[i4];
            const float4 xx = x4[i4];
            s[j].x = a.x + bb.x + 2.0f * xx.x;
            s[j].y = a.y + bb.y + 2.0f * xx.y;
            s[j].z = a.z + bb.z + 2.0f * xx.z;
            s[j].w = a.w + bb.w + 2.0f * xx.w;
            t[j] = make_float4(0.f, 0.f, 0.f, 0.f);
        }

        #pragma unroll 2
        for (int o = 0; o < Cv; ++o) {
            // gate partial dot over own 8 channels, 4 locations at once
            const float4* gr = reinterpret_cast<const float4*>(&gw[(o << 6) + c0]);
            const float4 w0 = gr[0], w1 = gr[1];
            float4 P = make_float4(0.f, 0.f, 0.f, 0.f);
            fma_bcast(w0.x, s[0], P); fma_bcast(w0.y, s[1], P);
            fma_bcast(w0.z, s[2], P); fma_bcast(w0.w, s[3], P);
            fma_bcast(w1.x, s[4], P); fma_bcast(w1.y, s[5], P);
            fma_bcast(w1.z, s[6], P); fma_bcast(w1.w, s[7], P);
            oct_reduce(P);                       // full 64-ch dot on all 8 lanes

            const float gb = gb2[o];
            const float4 xq = x4[b4 + o * L4];   // cluster's x at channel o (L1/L2)
            float4 acc;
            acc.x = xq.x * (P.x + gb);
            acc.y = xq.y * (P.y + gb);
            acc.z = xq.z * (P.z + gb);
            acc.w = xq.w * (P.w + gb);

            // scatter into own 8 output channels
            const float4* fr = reinterpret_cast<const float4*>(&fwT[(o << 6) + c0]);
            const float4 f0 = fr[0], f1 = fr[1];
            fma_bcast(f0.x, acc, t[0]); fma_bcast(f0.y, acc, t[1]);
            fma_bcast(f0.z, acc, t[2]); fma_bcast(f0.w, acc, t[3]);
            fma_bcast(f1.x, acc, t[4]); fma_bcast(f1.y, acc, t[5]);
            fma_bcast(f1.z, acc, t[6]); fma_bcast(f1.w, acc, t[7]);
        }

        // Epilogue: bias + residual + ReLU, store pre-GN output, local stats.
        #pragma unroll
        for (int j = 0; j < 8; ++j) {
            const int i4 = b4 + (c0 + j) * L4;
            const float4 r  = rs4[i4];
            const float fbias = fb[c0 + j];
            float4 v;
            v.x = fmaxf(t[j].x + fbias + r.x, 0.0f);
            v.y = fmaxf(t[j].y + fbias + r.y, 0.0f);
            v.z = fmaxf(t[j].z + fbias + r.z, 0.0f);
            v.w = fmaxf(t[j].w + fbias + r.w, 0.0f);
            o4[i4] = v;
            lsum += (v.x + v.y) + (v.z + v.w);
            lsq = fmaf(v.x, v.x, lsq);
            lsq = fmaf(v.y, v.y, lsq);
            lsq = fmaf(v.z, v.z, lsq);
            lsq = fmaf(v.w, v.w, lsq);
        }
    }

    r1[tid] = lsum; r2[tid] = lsq;
    __syncthreads();
    #pragma unroll
    for (int st = TPB / 2; st > 0; st >>= 1) {
        if (tid < st) { r1[tid] += r1[tid + st]; r2[tid] += r2[tid + st]; }
        __syncthreads();
    }
    if (tid == 0) {
        partials[2 * blockIdx.x]     = r1[0];
        partials[2 * blockIdx.x + 1] = r2[0];
    }
}

// ---------------------------------------------------------------------------
// Pass 2: reduce 256 partials per batch -> per-(b,c) scale/bias.
// ---------------------------------------------------------------------------
__global__ __launch_bounds__(256)
void pass2(const float* __restrict__ partials, const float* __restrict__ gn_w,
           const float* __restrict__ gn_b, float* __restrict__ sb)
{
    __shared__ float r1[256], r2[256];
    __shared__ float mean_s, rs_s;
    const int b = blockIdx.x, tid = threadIdx.x;
    r1[tid] = partials[2 * (b * 256 + tid)];
    r2[tid] = partials[2 * (b * 256 + tid) + 1];
    __syncthreads();
    #pragma unroll
    for (int st = 128; st > 0; st >>= 1) {
        if (tid < st) { r1[tid] += r1[tid + st]; r2[tid] += r2[tid + st]; }
        __syncthreads();
    }
    if (tid == 0) {
        const float n = (float)Cv * (float)Lv;
        const float mean = r1[0] / n;
        const float var  = r2[0] / n - mean * mean;
        mean_s = mean;
        rs_s   = rsqrtf(var + 1e-5f);
    }
    __syncthreads();
    if (tid < Cv) {
        const float sc = gn_w[tid] * rs_s;
        sb[b * Cv + tid]           = sc;
        sb[Bv * Cv + b * Cv + tid] = fmaf(-mean_s, sc, gn_b[tid]);
    }
}

// ---------------------------------------------------------------------------
// Pass 3: in-place GroupNorm affine on d_out (float4 vectorized).
// ---------------------------------------------------------------------------
__global__ __launch_bounds__(256)
void pass3(float* __restrict__ out, const float* __restrict__ sb)
{
    const int total4 = (Bv * Cv * Lv) / 4;   // 8388608
    for (int i = blockIdx.x * blockDim.x + threadIdx.x; i < total4;
         i += gridDim.x * blockDim.x) {
        const int row = i >> 14;            // / (L/4): row = b*64 + c
        const float sc = sb[row];
        const float bi = sb[Bv * Cv + row];
        float4 v = reinterpret_cast<float4*>(out)[i];
        v.x = fmaf(v.x, sc, bi);
        v.y = fmaf(v.y, sc, bi);
        v.z = fmaf(v.z, sc, bi);
        v.w = fmaf(v.w, sc, bi);
        reinterpret_cast<float4*>(out)[i] = v;
    }
}

extern "C" void kernel_launch(void* const* d_in, const int* in_sizes, int n_in,
                              void* d_out, int out_size, void* d_ws, size_t ws_size,
                              hipStream_t stream)
{
    const float* x      = (const float*)d_in[0];
    const float* inj0   = (const float*)d_in[1];
    const float* inj1   = (const float*)d_in[2];
    const float* resid  = (const float*)d_in[3];
    const float* gate_w = (const float*)d_in[4];
    const float* gate_b = (const float*)d_in[5];
    const float* fuse_w = (const float*)d_in[6];
    const float* fuse_b = (const float*)d_in[7];
    const float* gn_w   = (const float*)d_in[8];
    const float* gn_b   = (const float*)d_in[9];

    float* out      = (float*)d_out;
    float* ws       = (float*)d_ws;
    float* partials = ws;                 // 2 * 2048 floats = 16 KiB
    float* sb       = ws + 2 * GRID1;     // 2 * 512 floats  =  4 KiB

    hipLaunchKernelGGL(pass1, dim3(GRID1), dim3(TPB), 0, stream,
                       x, inj0, inj1, resid, gate_w, gate_b, fuse_w, fuse_b,
                       out, partials);
    hipLaunchKernelGGL(pass2, dim3(Bv), dim3(256), 0, stream,
                       partials, gn_w, gn_b, sb);
    hipLaunchKernelGGL(pass3, dim3(2048), dim3(256), 0, stream, out, sb);
}

// Round 5
// 304.208 us; speedup vs baseline: 1.1410x; 1.1410x over previous
//
#include <hip/hip_runtime.h>
#include <stdint.h>

#define Bv 8
#define Cv 64
#define Lv 65536
#define TPB 256
#define LOCS_PER_BLK 256              // 2 halves x 128
#define HALF_LOCS 128
#define BLKS_PER_B (Lv / LOCS_PER_BLK) // 256
#define GRID1 (Bv * BLKS_PER_B)        // 2048

// workspace: partials 2*2048 floats (16 KiB) + sb 1024 floats (4 KiB) = 20 KiB
// (proven footprint; R3's 36 KiB overflowed ws)

typedef __attribute__((ext_vector_type(8))) short short8;
typedef __attribute__((ext_vector_type(4))) float f32x4;

__device__ __forceinline__ uint16_t f2bf(float f) {
    uint32_t u = __float_as_uint(f);
    uint32_t r = u + 0x7FFFu + ((u >> 16) & 1u);   // round-to-nearest-even
    return (uint16_t)(r >> 16);
}
__device__ __forceinline__ uint32_t pack2bf(float lo, float hi) {
    return (uint32_t)f2bf(lo) | ((uint32_t)f2bf(hi) << 16);
}

// ---------------------------------------------------------------------------
// Pass 1 (MFMA): out = relu(Wf·(x ⊙ (Wg·s + 2bg)) + bf + resid), s=i0+i1+2x
// s_lds: bf16 k-pair layout [32 kpairs][130 locs] (dword = {ch 2kp, ch 2kp+1})
// w_lds: bf16 k-pair layout [2][64 rows][36] (row-major per output channel)
// Wave w owns cols [32w, 32w+32): after the prologue barrier, no further
// barriers needed within a half (reads/writes stay in the wave's slab).
// ---------------------------------------------------------------------------
__global__ void pass1(const float* __restrict__ x, const float* __restrict__ inj0,
                      const float* __restrict__ inj1, const float* __restrict__ resid,
                      const float* __restrict__ gate_w, const float* __restrict__ gate_b,
                      const float* __restrict__ fuse_w, const float* __restrict__ fuse_b,
                      float* __restrict__ out, float* __restrict__ partials)
{
    __shared__ uint32_t s_lds[32][130];
    __shared__ uint32_t w_lds[2][64][36];
    __shared__ float r1[TPB], r2[TPB];

    const int tid  = threadIdx.x;
    const int lane = tid & 63;
    const int w    = tid >> 6;     // wave 0..3
    const int g    = lane >> 4;    // k-group 0..3
    const int ln   = lane & 15;    // 0..15

    const int b    = blockIdx.x >> 8;
    const int lb   = blockIdx.x & 255;
    const int bCL  = b * (Cv * Lv);

    // ---- stage weights (once): thread t covers row m=t>>2, k0=(t&3)*16 ----
    {
        const int m  = tid >> 2;
        const int k0 = (tid & 3) << 4;
        const float4* wg4 = reinterpret_cast<const float4*>(gate_w + m * 64 + k0);
        const float4* wf4 = reinterpret_cast<const float4*>(fuse_w + m * 64 + k0);
        uint32_t* dg = &w_lds[0][m][k0 >> 1];
        uint32_t* df = &w_lds[1][m][k0 >> 1];
        #pragma unroll
        for (int q = 0; q < 4; ++q) {
            const float4 vg = wg4[q];
            dg[2 * q]     = pack2bf(vg.x, vg.y);
            dg[2 * q + 1] = pack2bf(vg.z, vg.w);
            const float4 vf = wf4[q];
            df[2 * q]     = pack2bf(vf.x, vf.y);
            df[2 * q + 1] = pack2bf(vf.z, vf.w);
        }
    }

    float lsum = 0.0f, lsq = 0.0f;

    #pragma unroll 1
    for (int h = 0; h < 2; ++h) {
        if (h) __syncthreads();             // prev readers done before rewrite
        const int col0 = lb * LOCS_PER_BLK + h * HALF_LOCS;

        // ---- prologue: stage s = i0 + i1 + 2x as bf16 pairs ----
        {
            const int cp = tid & 63;        // column pair
            const int l0 = 2 * cp;
            #pragma unroll
            for (int it = 0; it < 8; ++it) {
                const int kp = 4 * it + (tid >> 6);
                const int c0 = 2 * kp;
                const int ia = bCL + c0 * Lv + col0 + l0;
                const float2 xa = *reinterpret_cast<const float2*>(x    + ia);
                const float2 aa = *reinterpret_cast<const float2*>(inj0 + ia);
                const float2 ba = *reinterpret_cast<const float2*>(inj1 + ia);
                const int ib = ia + Lv;
                const float2 xb = *reinterpret_cast<const float2*>(x    + ib);
                const float2 ab = *reinterpret_cast<const float2*>(inj0 + ib);
                const float2 bb = *reinterpret_cast<const float2*>(inj1 + ib);
                const float s0x = aa.x + ba.x + 2.0f * xa.x;
                const float s0y = aa.y + ba.y + 2.0f * xa.y;
                const float s1x = ab.x + bb.x + 2.0f * xb.x;
                const float s1y = ab.y + bb.y + 2.0f * xb.y;
                uint2 dw;
                dw.x = pack2bf(s0x, s1x);   // col l0  : {ch c0, ch c0+1}
                dw.y = pack2bf(s0y, s1y);   // col l0+1: {ch c0, ch c0+1}
                *reinterpret_cast<uint2*>(&s_lds[kp][l0]) = dw;
            }
        }
        __syncthreads();

        // ---- GEMM1: g = Wg . s + 2*gate_b ----
        f32x4 D1[4][2];
        #pragma unroll
        for (int oc = 0; oc < 4; ++oc) {
            #pragma unroll
            for (int j = 0; j < 4; ++j) {
                const float gb = 2.0f * gate_b[16 * oc + 4 * g + j];
                D1[oc][0][j] = gb;
                D1[oc][1][j] = gb;
            }
        }
        #pragma unroll
        for (int nt = 0; nt < 2; ++nt) {
            const int n = ln + 16 * (2 * w + nt);
            uint4 B0, B1;
            B0.x = s_lds[4 * g + 0][n];  B0.y = s_lds[4 * g + 1][n];
            B0.z = s_lds[4 * g + 2][n];  B0.w = s_lds[4 * g + 3][n];
            B1.x = s_lds[4 * g + 16][n]; B1.y = s_lds[4 * g + 17][n];
            B1.z = s_lds[4 * g + 18][n]; B1.w = s_lds[4 * g + 19][n];
            #pragma unroll
            for (int oc = 0; oc < 4; ++oc) {
                const int m = ln + 16 * oc;
                const uint4 A0 = *reinterpret_cast<const uint4*>(&w_lds[0][m][4 * g]);
                const uint4 A1 = *reinterpret_cast<const uint4*>(&w_lds[0][m][4 * g + 16]);
                D1[oc][nt] = __builtin_amdgcn_mfma_f32_16x16x32_bf16(
                    __builtin_bit_cast(short8, A0), __builtin_bit_cast(short8, B0),
                    D1[oc][nt], 0, 0, 0);
                D1[oc][nt] = __builtin_amdgcn_mfma_f32_16x16x32_bf16(
                    __builtin_bit_cast(short8, A1), __builtin_bit_cast(short8, B1),
                    D1[oc][nt], 0, 0, 0);
            }
        }

        // ---- acc = x * g  -> overwrite s_lds (own slab only) ----
        #pragma unroll
        for (int nt = 0; nt < 2; ++nt) {
            const int n  = ln + 16 * (2 * w + nt);
            const int cg = bCL + col0 + n;
            #pragma unroll
            for (int oc = 0; oc < 4; ++oc) {
                const int m0 = 16 * oc + 4 * g;
                float av[4];
                #pragma unroll
                for (int j = 0; j < 4; ++j)
                    av[j] = x[cg + (m0 + j) * Lv] * D1[oc][nt][j];
                s_lds[8 * oc + 2 * g][n]     = pack2bf(av[0], av[1]);
                s_lds[8 * oc + 2 * g + 1][n] = pack2bf(av[2], av[3]);
            }
        }

        // ---- GEMM2: u = Wf . acc + fuse_b + resid ----
        f32x4 D2[4][2];
        #pragma unroll
        for (int nt = 0; nt < 2; ++nt) {
            const int n  = ln + 16 * (2 * w + nt);
            const int cg = bCL + col0 + n;
            #pragma unroll
            for (int oc = 0; oc < 4; ++oc) {
                #pragma unroll
                for (int j = 0; j < 4; ++j) {
                    const int m = 16 * oc + 4 * g + j;
                    D2[oc][nt][j] = fuse_b[m] + resid[cg + m * Lv];
                }
            }
        }
        #pragma unroll
        for (int nt = 0; nt < 2; ++nt) {
            const int n = ln + 16 * (2 * w + nt);
            uint4 B0, B1;
            B0.x = s_lds[4 * g + 0][n];  B0.y = s_lds[4 * g + 1][n];
            B0.z = s_lds[4 * g + 2][n];  B0.w = s_lds[4 * g + 3][n];
            B1.x = s_lds[4 * g + 16][n]; B1.y = s_lds[4 * g + 17][n];
            B1.z = s_lds[4 * g + 18][n]; B1.w = s_lds[4 * g + 19][n];
            #pragma unroll
            for (int oc = 0; oc < 4; ++oc) {
                const int m = ln + 16 * oc;
                const uint4 A0 = *reinterpret_cast<const uint4*>(&w_lds[1][m][4 * g]);
                const uint4 A1 = *reinterpret_cast<const uint4*>(&w_lds[1][m][4 * g + 16]);
                D2[oc][nt] = __builtin_amdgcn_mfma_f32_16x16x32_bf16(
                    __builtin_bit_cast(short8, A0), __builtin_bit_cast(short8, B0),
                    D2[oc][nt], 0, 0, 0);
                D2[oc][nt] = __builtin_amdgcn_mfma_f32_16x16x32_bf16(
                    __builtin_bit_cast(short8, A1), __builtin_bit_cast(short8, B1),
                    D2[oc][nt], 0, 0, 0);
            }
        }

        // ---- epilogue: ReLU, store, stats ----
        #pragma unroll
        for (int nt = 0; nt < 2; ++nt) {
            const int n  = ln + 16 * (2 * w + nt);
            const int cg = bCL + col0 + n;
            #pragma unroll
            for (int oc = 0; oc < 4; ++oc) {
                #pragma unroll
                for (int j = 0; j < 4; ++j) {
                    const int m = 16 * oc + 4 * g + j;
                    const float v = fmaxf(D2[oc][nt][j], 0.0f);
                    out[cg + m * Lv] = v;
                    lsum += v;
                    lsq  = fmaf(v, v, lsq);
                }
            }
        }
    }

    // ---- deterministic block reduction -> per-block partials ----
    r1[tid] = lsum; r2[tid] = lsq;
    __syncthreads();
    #pragma unroll
    for (int st = TPB / 2; st > 0; st >>= 1) {
        if (tid < st) { r1[tid] += r1[tid + st]; r2[tid] += r2[tid + st]; }
        __syncthreads();
    }
    if (tid == 0) {
        partials[2 * blockIdx.x]     = r1[0];
        partials[2 * blockIdx.x + 1] = r2[0];
    }
}

// ---------------------------------------------------------------------------
// Pass 2: reduce 256 partials per batch -> per-(b,c) scale/bias.
// ---------------------------------------------------------------------------
__global__ __launch_bounds__(256)
void pass2(const float* __restrict__ partials, const float* __restrict__ gn_w,
           const float* __restrict__ gn_b, float* __restrict__ sb)
{
    __shared__ float r1[256], r2[256];
    __shared__ float mean_s, rs_s;
    const int b = blockIdx.x, tid = threadIdx.x;
    r1[tid] = partials[2 * (b * 256 + tid)];
    r2[tid] = partials[2 * (b * 256 + tid) + 1];
    __syncthreads();
    #pragma unroll
    for (int st = 128; st > 0; st >>= 1) {
        if (tid < st) { r1[tid] += r1[tid + st]; r2[tid] += r2[tid + st]; }
        __syncthreads();
    }
    if (tid == 0) {
        const float n = (float)Cv * (float)Lv;
        const float mean = r1[0] / n;
        const float var  = r2[0] / n - mean * mean;
        mean_s = mean;
        rs_s   = rsqrtf(var + 1e-5f);
    }
    __syncthreads();
    if (tid < Cv) {
        const float sc = gn_w[tid] * rs_s;
        sb[b * Cv + tid]           = sc;
        sb[Bv * Cv + b * Cv + tid] = fmaf(-mean_s, sc, gn_b[tid]);
    }
}

// ---------------------------------------------------------------------------
// Pass 3: in-place GroupNorm affine on d_out (float4 vectorized).
// ---------------------------------------------------------------------------
__global__ __launch_bounds__(256)
void pass3(float* __restrict__ out, const float* __restrict__ sb)
{
    const int total4 = (Bv * Cv * Lv) / 4;   // 8388608
    for (int i = blockIdx.x * blockDim.x + threadIdx.x; i < total4;
         i += gridDim.x * blockDim.x) {
        const int row = i >> 14;            // / (L/4): row = b*64 + c
        const float sc = sb[row];
        const float bi = sb[Bv * Cv + row];
        float4 v = reinterpret_cast<float4*>(out)[i];
        v.x = fmaf(v.x, sc, bi);
        v.y = fmaf(v.y, sc, bi);
        v.z = fmaf(v.z, sc, bi);
        v.w = fmaf(v.w, sc, bi);
        reinterpret_cast<float4*>(out)[i] = v;
    }
}

extern "C" void kernel_launch(void* const* d_in, const int* in_sizes, int n_in,
                              void* d_out, int out_size, void* d_ws, size_t ws_size,
                              hipStream_t stream)
{
    const float* x      = (const float*)d_in[0];
    const float* inj0   = (const float*)d_in[1];
    const float* inj1   = (const float*)d_in[2];
    const float* resid  = (const float*)d_in[3];
    const float* gate_w = (const float*)d_in[4];
    const float* gate_b = (const float*)d_in[5];
    const float* fuse_w = (const float*)d_in[6];
    const float* fuse_b = (const float*)d_in[7];
    const float* gn_w   = (const float*)d_in[8];
    const float* gn_b   = (const float*)d_in[9];

    float* out      = (float*)d_out;
    float* ws       = (float*)d_ws;
    float* partials = ws;                 // 2 * 2048 floats = 16 KiB
    float* sb       = ws + 2 * GRID1;     // 2 * 512 floats  =  4 KiB

    hipLaunchKernelGGL(pass1, dim3(GRID1), dim3(TPB), 0, stream,
                       x, inj0, inj1, resid, gate_w, gate_b, fuse_w, fuse_b,
                       out, partials);
    hipLaunchKernelGGL(pass2, dim3(Bv), dim3(256), 0, stream,
                       partials, gn_w, gn_b, sb);
    hipLaunchKernelGGL(pass3, dim3(2048), dim3(256), 0, stream, out, sb);
}

// Round 6
// 256.425 us; speedup vs baseline: 1.3536x; 1.1863x over previous
//
#include <hip/hip_runtime.h>
#include <stdint.h>

#define Bv 8
#define Cv 64
#define Lv 65536
#define TPB 256
#define LOCS_PER_BLK 256              // 2 halves x 128
#define HALF_LOCS 128
#define BLKS_PER_B (Lv / LOCS_PER_BLK) // 256
#define GRID1 (Bv * BLKS_PER_B)        // 2048

// workspace: partials 2*2048 floats (16 KiB) + sb 1024 floats (4 KiB) = 20 KiB
// (proven footprint; do not grow — R3's 36 KiB overflowed ws)

typedef __attribute__((ext_vector_type(8))) short short8;
typedef __attribute__((ext_vector_type(4))) float f32x4;

#define SSTRIDE 132   // dwords per row of s_buf; 132*4=528B: row start 16B-aligned,
                      // shifts bank clusters by 1 per row -> balanced float4 reads

__device__ __forceinline__ uint16_t f2bf(float f) {
    uint32_t u = __float_as_uint(f);
    uint32_t r = u + 0x7FFFu + ((u >> 16) & 1u);   // round-to-nearest-even
    return (uint16_t)(r >> 16);
}
__device__ __forceinline__ uint32_t pack2bf(float lo, float hi) {
    return (uint32_t)f2bf(lo) | ((uint32_t)f2bf(hi) << 16);
}

// ---------------------------------------------------------------------------
// Pass 1 (MFMA): out = relu(Wf·(x ⊙ (Wg·s + 2bg)) + bf + resid), s=i0+i1+2x
// s_buf (union):
//   phase A: bf16 k-pair staging [32 kpairs][SSTRIDE] (dword={ch 2kp,ch 2kp+1})
//   phase B: f32 epilogue tile  [32 rows][SSTRIDE]
// w_lds: bf16 k-pair weights [2][64][36].
// Wave w owns cols [32w,32w+32) through the GEMM phases (no intra-half
// barriers there); epilogue re-layouts through s_buf with 2 chunk barriers.
// ---------------------------------------------------------------------------
__global__ void pass1(const float* __restrict__ x, const float* __restrict__ inj0,
                      const float* __restrict__ inj1, const float* __restrict__ resid,
                      const float* __restrict__ gate_w, const float* __restrict__ gate_b,
                      const float* __restrict__ fuse_w, const float* __restrict__ fuse_b,
                      float* __restrict__ out, float* __restrict__ partials)
{
    __shared__ uint32_t s_buf[32 * SSTRIDE];
    __shared__ uint32_t w_lds[2][64][36];
    __shared__ float r1[TPB], r2[TPB];

    const int tid  = threadIdx.x;
    const int lane = tid & 63;
    const int w    = tid >> 6;     // wave 0..3
    const int g    = lane >> 4;    // k-group 0..3
    const int ln   = lane & 15;    // 0..15

    const int b    = blockIdx.x >> 8;
    const int lb   = blockIdx.x & 255;
    const int bCL  = b * (Cv * Lv);

    // ---- stage weights (once): thread t covers row m=t>>2, k0=(t&3)*16 ----
    {
        const int m  = tid >> 2;
        const int k0 = (tid & 3) << 4;
        const float4* wg4 = reinterpret_cast<const float4*>(gate_w + m * 64 + k0);
        const float4* wf4 = reinterpret_cast<const float4*>(fuse_w + m * 64 + k0);
        uint32_t* dg = &w_lds[0][m][k0 >> 1];
        uint32_t* df = &w_lds[1][m][k0 >> 1];
        #pragma unroll
        for (int q = 0; q < 4; ++q) {
            const float4 vg = wg4[q];
            dg[2 * q]     = pack2bf(vg.x, vg.y);
            dg[2 * q + 1] = pack2bf(vg.z, vg.w);
            const float4 vf = wf4[q];
            df[2 * q]     = pack2bf(vf.x, vf.y);
            df[2 * q + 1] = pack2bf(vf.z, vf.w);
        }
    }

    // ---- per-lane C-init constants (depend on g only) ----
    f32x4 gbi[4], fbi[4];
    #pragma unroll
    for (int oc = 0; oc < 4; ++oc)
        #pragma unroll
        for (int j = 0; j < 4; ++j) {
            gbi[oc][j] = 2.0f * gate_b[16 * oc + 4 * g + j];
            fbi[oc][j] = fuse_b[16 * oc + 4 * g + j];
        }

    float lsum = 0.0f, lsq = 0.0f;

    #pragma unroll 1
    for (int h = 0; h < 2; ++h) {
        const int col0 = lb * LOCS_PER_BLK + h * HALF_LOCS;

        // ---- phase A: stage s = i0 + i1 + 2x as bf16 pairs ----
        {
            const int l0 = 2 * (tid & 63);        // column (even)
            #pragma unroll
            for (int it = 0; it < 8; ++it) {
                const int kp = 4 * it + (tid >> 6);
                const int c0 = 2 * kp;
                const int ia = bCL + c0 * Lv + col0 + l0;
                const float2 xa = *reinterpret_cast<const float2*>(x    + ia);
                const float2 aa = *reinterpret_cast<const float2*>(inj0 + ia);
                const float2 ba = *reinterpret_cast<const float2*>(inj1 + ia);
                const int ib = ia + Lv;
                const float2 xb = *reinterpret_cast<const float2*>(x    + ib);
                const float2 ab = *reinterpret_cast<const float2*>(inj0 + ib);
                const float2 bb = *reinterpret_cast<const float2*>(inj1 + ib);
                uint2 dw;
                dw.x = pack2bf(aa.x + ba.x + 2.0f * xa.x, ab.x + bb.x + 2.0f * xb.x);
                dw.y = pack2bf(aa.y + ba.y + 2.0f * xa.y, ab.y + bb.y + 2.0f * xb.y);
                *reinterpret_cast<uint2*>(&s_buf[kp * SSTRIDE + l0]) = dw;
            }
        }
        __syncthreads();

        // ---- GEMM1: g = Wg . s + 2*gate_b ----
        f32x4 D1[4][2];
        #pragma unroll
        for (int oc = 0; oc < 4; ++oc) { D1[oc][0] = gbi[oc]; D1[oc][1] = gbi[oc]; }
        #pragma unroll
        for (int nt = 0; nt < 2; ++nt) {
            const int n = ln + 16 * (2 * w + nt);
            uint4 B0, B1;
            B0.x = s_buf[(4 * g + 0) * SSTRIDE + n];  B0.y = s_buf[(4 * g + 1) * SSTRIDE + n];
            B0.z = s_buf[(4 * g + 2) * SSTRIDE + n];  B0.w = s_buf[(4 * g + 3) * SSTRIDE + n];
            B1.x = s_buf[(4 * g + 16) * SSTRIDE + n]; B1.y = s_buf[(4 * g + 17) * SSTRIDE + n];
            B1.z = s_buf[(4 * g + 18) * SSTRIDE + n]; B1.w = s_buf[(4 * g + 19) * SSTRIDE + n];
            #pragma unroll
            for (int oc = 0; oc < 4; ++oc) {
                const int m = ln + 16 * oc;
                const uint4 A0 = *reinterpret_cast<const uint4*>(&w_lds[0][m][4 * g]);
                const uint4 A1 = *reinterpret_cast<const uint4*>(&w_lds[0][m][4 * g + 16]);
                D1[oc][nt] = __builtin_amdgcn_mfma_f32_16x16x32_bf16(
                    __builtin_bit_cast(short8, A0), __builtin_bit_cast(short8, B0),
                    D1[oc][nt], 0, 0, 0);
                D1[oc][nt] = __builtin_amdgcn_mfma_f32_16x16x32_bf16(
                    __builtin_bit_cast(short8, A1), __builtin_bit_cast(short8, B1),
                    D1[oc][nt], 0, 0, 0);
            }
        }

        // ---- acc = x * g  -> overwrite s_buf (own column slab only) ----
        #pragma unroll
        for (int nt = 0; nt < 2; ++nt) {
            const int n  = ln + 16 * (2 * w + nt);
            const int cg = bCL + col0 + n;
            #pragma unroll
            for (int oc = 0; oc < 4; ++oc) {
                const int m0 = 16 * oc + 4 * g;
                float av[4];
                #pragma unroll
                for (int j = 0; j < 4; ++j)
                    av[j] = x[cg + (m0 + j) * Lv] * D1[oc][nt][j];
                s_buf[(8 * oc + 2 * g) * SSTRIDE + n]     = pack2bf(av[0], av[1]);
                s_buf[(8 * oc + 2 * g + 1) * SSTRIDE + n] = pack2bf(av[2], av[3]);
            }
        }

        // ---- GEMM2: u = Wf . acc + fuse_b ----
        f32x4 D2[4][2];
        #pragma unroll
        for (int oc = 0; oc < 4; ++oc) { D2[oc][0] = fbi[oc]; D2[oc][1] = fbi[oc]; }
        #pragma unroll
        for (int nt = 0; nt < 2; ++nt) {
            const int n = ln + 16 * (2 * w + nt);
            uint4 B0, B1;
            B0.x = s_buf[(4 * g + 0) * SSTRIDE + n];  B0.y = s_buf[(4 * g + 1) * SSTRIDE + n];
            B0.z = s_buf[(4 * g + 2) * SSTRIDE + n];  B0.w = s_buf[(4 * g + 3) * SSTRIDE + n];
            B1.x = s_buf[(4 * g + 16) * SSTRIDE + n]; B1.y = s_buf[(4 * g + 17) * SSTRIDE + n];
            B1.z = s_buf[(4 * g + 18) * SSTRIDE + n]; B1.w = s_buf[(4 * g + 19) * SSTRIDE + n];
            #pragma unroll
            for (int oc = 0; oc < 4; ++oc) {
                const int m = ln + 16 * oc;
                const uint4 A0 = *reinterpret_cast<const uint4*>(&w_lds[1][m][4 * g]);
                const uint4 A1 = *reinterpret_cast<const uint4*>(&w_lds[1][m][4 * g + 16]);
                D2[oc][nt] = __builtin_amdgcn_mfma_f32_16x16x32_bf16(
                    __builtin_bit_cast(short8, A0), __builtin_bit_cast(short8, B0),
                    D2[oc][nt], 0, 0, 0);
                D2[oc][nt] = __builtin_amdgcn_mfma_f32_16x16x32_bf16(
                    __builtin_bit_cast(short8, A1), __builtin_bit_cast(short8, B1),
                    D2[oc][nt], 0, 0, 0);
            }
        }

        // ---- epilogue via LDS re-layout: +resid, ReLU, stats, coalesced store
        float* uf = reinterpret_cast<float*>(s_buf);
        const int rowin = tid >> 3;          // 0..31: LDS row
        const int cl    = tid & 7;           // 8 lanes x float4 = 128B per row
        #pragma unroll 1
        for (int ch = 0; ch < 2; ++ch) {
            // fragments -> u tile (rows m&31, own col slab: no barrier needed)
            #pragma unroll
            for (int oc = 2 * ch; oc < 2 * ch + 2; ++oc)
                #pragma unroll
                for (int nt = 0; nt < 2; ++nt) {
                    const int n = ln + 16 * (2 * w + nt);
                    #pragma unroll
                    for (int j = 0; j < 4; ++j) {
                        const int mr = (16 * oc + 4 * g + j) & 31;
                        uf[mr * SSTRIDE + n] = D2[oc][nt][j];
                    }
                }
            __syncthreads();
            const int m  = 32 * ch + rowin;
            const int gb = bCL + m * Lv + col0;
            #pragma unroll
            for (int i = 0; i < 4; ++i) {
                const int c = 4 * (cl + 8 * i);
                float4 v = *reinterpret_cast<const float4*>(&uf[rowin * SSTRIDE + c]);
                const float4 r = *reinterpret_cast<const float4*>(&resid[gb + c]);
                v.x = fmaxf(v.x + r.x, 0.0f);
                v.y = fmaxf(v.y + r.y, 0.0f);
                v.z = fmaxf(v.z + r.z, 0.0f);
                v.w = fmaxf(v.w + r.w, 0.0f);
                *reinterpret_cast<float4*>(&out[gb + c]) = v;
                lsum += (v.x + v.y) + (v.z + v.w);
                lsq = fmaf(v.x, v.x, lsq);
                lsq = fmaf(v.y, v.y, lsq);
                lsq = fmaf(v.z, v.z, lsq);
                lsq = fmaf(v.w, v.w, lsq);
            }
            __syncthreads();   // tile reads done before reuse (next chunk/half)
        }
    }

    // ---- deterministic block reduction -> per-block partials ----
    r1[tid] = lsum; r2[tid] = lsq;
    __syncthreads();
    #pragma unroll
    for (int st = TPB / 2; st > 0; st >>= 1) {
        if (tid < st) { r1[tid] += r1[tid + st]; r2[tid] += r2[tid + st]; }
        __syncthreads();
    }
    if (tid == 0) {
        partials[2 * blockIdx.x]     = r1[0];
        partials[2 * blockIdx.x + 1] = r2[0];
    }
}

// ---------------------------------------------------------------------------
// Pass 2: reduce 256 partials per batch -> per-(b,c) scale/bias.
// ---------------------------------------------------------------------------
__global__ __launch_bounds__(256)
void pass2(const float* __restrict__ partials, const float* __restrict__ gn_w,
           const float* __restrict__ gn_b, float* __restrict__ sb)
{
    __shared__ float r1[256], r2[256];
    __shared__ float mean_s, rs_s;
    const int b = blockIdx.x, tid = threadIdx.x;
    r1[tid] = partials[2 * (b * 256 + tid)];
    r2[tid] = partials[2 * (b * 256 + tid) + 1];
    __syncthreads();
    #pragma unroll
    for (int st = 128; st > 0; st >>= 1) {
        if (tid < st) { r1[tid] += r1[tid + st]; r2[tid] += r2[tid + st]; }
        __syncthreads();
    }
    if (tid == 0) {
        const float n = (float)Cv * (float)Lv;
        const float mean = r1[0] / n;
        const float var  = r2[0] / n - mean * mean;
        mean_s = mean;
        rs_s   = rsqrtf(var + 1e-5f);
    }
    __syncthreads();
    if (tid < Cv) {
        const float sc = gn_w[tid] * rs_s;
        sb[b * Cv + tid]           = sc;
        sb[Bv * Cv + b * Cv + tid] = fmaf(-mean_s, sc, gn_b[tid]);
    }
}

// ---------------------------------------------------------------------------
// Pass 3: in-place GroupNorm affine on d_out (float4 vectorized).
// ---------------------------------------------------------------------------
__global__ __launch_bounds__(256)
void pass3(float* __restrict__ out, const float* __restrict__ sb)
{
    const int total4 = (Bv * Cv * Lv) / 4;   // 8388608
    for (int i = blockIdx.x * blockDim.x + threadIdx.x; i < total4;
         i += gridDim.x * blockDim.x) {
        const int row = i >> 14;            // / (L/4): row = b*64 + c
        const float sc = sb[row];
        const float bi = sb[Bv * Cv + row];
        float4 v = reinterpret_cast<float4*>(out)[i];
        v.x = fmaf(v.x, sc, bi);
        v.y = fmaf(v.y, sc, bi);
        v.z = fmaf(v.z, sc, bi);
        v.w = fmaf(v.w, sc, bi);
        reinterpret_cast<float4*>(out)[i] = v;
    }
}

extern "C" void kernel_launch(void* const* d_in, const int* in_sizes, int n_in,
                              void* d_out, int out_size, void* d_ws, size_t ws_size,
                              hipStream_t stream)
{
    const float* x      = (const float*)d_in[0];
    const float* inj0   = (const float*)d_in[1];
    const float* inj1   = (const float*)d_in[2];
    const float* resid  = (const float*)d_in[3];
    const float* gate_w = (const float*)d_in[4];
    const float* gate_b = (const float*)d_in[5];
    const float* fuse_w = (const float*)d_in[6];
    const float* fuse_b = (const float*)d_in[7];
    const float* gn_w   = (const float*)d_in[8];
    const float* gn_b   = (const float*)d_in[9];

    float* out      = (float*)d_out;
    float* ws       = (float*)d_ws;
    float* partials = ws;                 // 2 * 2048 floats = 16 KiB
    float* sb       = ws + 2 * GRID1;     // 2 * 512 floats  =  4 KiB

    hipLaunchKernelGGL(pass1, dim3(GRID1), dim3(TPB), 0, stream,
                       x, inj0, inj1, resid, gate_w, gate_b, fuse_w, fuse_b,
                       out, partials);
    hipLaunchKernelGGL(pass2, dim3(Bv), dim3(256), 0, stream,
                       partials, gn_w, gn_b, sb);
    hipLaunchKernelGGL(pass3, dim3(2048), dim3(256), 0, stream, out, sb);
}

// Round 7
// 250.860 us; speedup vs baseline: 1.3837x; 1.0222x over previous
//
#include <hip/hip_runtime.h>
#include <stdint.h>

#define Bv 8
#define Cv 64
#define Lv 65536
#define TPB 256
#define LOCS_PER_BLK 256              // 2 halves x 128
#define HALF_LOCS 128
#define BLKS_PER_B (Lv / LOCS_PER_BLK) // 256
#define GRID1 (Bv * BLKS_PER_B)        // 2048

// workspace: partials 2*2048 floats (16 KiB) + sb 1024 floats (4 KiB) = 20 KiB
// (proven footprint; do not grow — R3's 36 KiB overflowed ws)

typedef __attribute__((ext_vector_type(8))) short short8;
typedef __attribute__((ext_vector_type(4))) float f32x4;

#define SSTRIDE 132   // dwords per row of s_buf; keeps float4 rows 16B-aligned
                      // and staggers bank clusters per row

__device__ __forceinline__ uint16_t f2bf(float f) {
    uint32_t u = __float_as_uint(f);
    uint32_t r = u + 0x7FFFu + ((u >> 16) & 1u);   // round-to-nearest-even
    return (uint16_t)(r >> 16);
}
__device__ __forceinline__ uint32_t pack2bf(float lo, float hi) {
    return (uint32_t)f2bf(lo) | ((uint32_t)f2bf(hi) << 16);
}

// ---------------------------------------------------------------------------
// Pass 1 (MFMA): out = relu(Wf·(x ⊙ (Wg·s + 2bg)) + bf + resid), s=i0+i1+2x
// Staging is float4-wide (24 loads/thread) to maximize bytes-in-flight —
// R6 was MLP-limited (2.7 TB/s eff with float2 staging at VGPR 64).
// ---------------------------------------------------------------------------
__global__ void pass1(const float* __restrict__ x, const float* __restrict__ inj0,
                      const float* __restrict__ inj1, const float* __restrict__ resid,
                      const float* __restrict__ gate_w, const float* __restrict__ gate_b,
                      const float* __restrict__ fuse_w, const float* __restrict__ fuse_b,
                      float* __restrict__ out, float* __restrict__ partials)
{
    __shared__ uint32_t s_buf[32 * SSTRIDE];
    __shared__ uint32_t w_lds[2][64][36];
    __shared__ float r1[TPB], r2[TPB];

    const int tid  = threadIdx.x;
    const int lane = tid & 63;
    const int w    = tid >> 6;     // wave 0..3
    const int g    = lane >> 4;    // k-group 0..3
    const int ln   = lane & 15;    // 0..15

    const int b    = blockIdx.x >> 8;
    const int lb   = blockIdx.x & 255;
    const int bCL  = b * (Cv * Lv);

    // ---- stage weights (once): thread t covers row m=t>>2, k0=(t&3)*16 ----
    {
        const int m  = tid >> 2;
        const int k0 = (tid & 3) << 4;
        const float4* wg4 = reinterpret_cast<const float4*>(gate_w + m * 64 + k0);
        const float4* wf4 = reinterpret_cast<const float4*>(fuse_w + m * 64 + k0);
        uint32_t* dg = &w_lds[0][m][k0 >> 1];
        uint32_t* df = &w_lds[1][m][k0 >> 1];
        #pragma unroll
        for (int q = 0; q < 4; ++q) {
            const float4 vg = wg4[q];
            dg[2 * q]     = pack2bf(vg.x, vg.y);
            dg[2 * q + 1] = pack2bf(vg.z, vg.w);
            const float4 vf = wf4[q];
            df[2 * q]     = pack2bf(vf.x, vf.y);
            df[2 * q + 1] = pack2bf(vf.z, vf.w);
        }
    }

    // ---- per-lane C-init constants (depend on g only) ----
    f32x4 gbi[4], fbi[4];
    #pragma unroll
    for (int oc = 0; oc < 4; ++oc)
        #pragma unroll
        for (int j = 0; j < 4; ++j) {
            gbi[oc][j] = 2.0f * gate_b[16 * oc + 4 * g + j];
            fbi[oc][j] = fuse_b[16 * oc + 4 * g + j];
        }

    const int rowin = tid >> 3;          // 0..31: epilogue LDS row
    const int cl    = tid & 7;           // 8 lanes x float4 = 128B per row

    float lsum = 0.0f, lsq = 0.0f;

    #pragma unroll 1
    for (int h = 0; h < 2; ++h) {
        const int col0 = lb * LOCS_PER_BLK + h * HALF_LOCS;

        // ---- phase A: stage s = i0 + i1 + 2x as bf16 pairs (float4 loads) --
        {
            const int kp  = tid >> 3;              // channel pair 0..31
            const int cq0 = tid & 7;               // col-quad base
            const int rA  = bCL + (2 * kp) * Lv + col0;
            const int rB  = rA + Lv;
            #pragma unroll
            for (int u = 0; u < 4; ++u) {
                const int c = 4 * (cq0 + 8 * u);   // col offset (floats)
                const float4 xA = *reinterpret_cast<const float4*>(x    + rA + c);
                const float4 aA = *reinterpret_cast<const float4*>(inj0 + rA + c);
                const float4 bA = *reinterpret_cast<const float4*>(inj1 + rA + c);
                const float4 xB = *reinterpret_cast<const float4*>(x    + rB + c);
                const float4 aB = *reinterpret_cast<const float4*>(inj0 + rB + c);
                const float4 bB = *reinterpret_cast<const float4*>(inj1 + rB + c);
                uint4 dw;
                dw.x = pack2bf(aA.x + bA.x + 2.0f * xA.x, aB.x + bB.x + 2.0f * xB.x);
                dw.y = pack2bf(aA.y + bA.y + 2.0f * xA.y, aB.y + bB.y + 2.0f * xB.y);
                dw.z = pack2bf(aA.z + bA.z + 2.0f * xA.z, aB.z + bB.z + 2.0f * xB.z);
                dw.w = pack2bf(aA.w + bA.w + 2.0f * xA.w, aB.w + bB.w + 2.0f * xB.w);
                *reinterpret_cast<uint4*>(&s_buf[kp * SSTRIDE + c]) = dw;
            }
        }
        __syncthreads();

        // ---- prefetch resid for epilogue chunk 0 (hides under GEMMs) ----
        float4 rp0[4];
        {
            const int gb0 = bCL + rowin * Lv + col0;
            #pragma unroll
            for (int i = 0; i < 4; ++i)
                rp0[i] = *reinterpret_cast<const float4*>(&resid[gb0 + 4 * (cl + 8 * i)]);
        }

        // ---- GEMM1: g = Wg . s + 2*gate_b ----
        f32x4 D1[4][2];
        #pragma unroll
        for (int oc = 0; oc < 4; ++oc) { D1[oc][0] = gbi[oc]; D1[oc][1] = gbi[oc]; }
        #pragma unroll
        for (int nt = 0; nt < 2; ++nt) {
            const int n = ln + 16 * (2 * w + nt);
            uint4 B0, B1;
            B0.x = s_buf[(4 * g + 0) * SSTRIDE + n];  B0.y = s_buf[(4 * g + 1) * SSTRIDE + n];
            B0.z = s_buf[(4 * g + 2) * SSTRIDE + n];  B0.w = s_buf[(4 * g + 3) * SSTRIDE + n];
            B1.x = s_buf[(4 * g + 16) * SSTRIDE + n]; B1.y = s_buf[(4 * g + 17) * SSTRIDE + n];
            B1.z = s_buf[(4 * g + 18) * SSTRIDE + n]; B1.w = s_buf[(4 * g + 19) * SSTRIDE + n];
            #pragma unroll
            for (int oc = 0; oc < 4; ++oc) {
                const int m = ln + 16 * oc;
                const uint4 A0 = *reinterpret_cast<const uint4*>(&w_lds[0][m][4 * g]);
                const uint4 A1 = *reinterpret_cast<const uint4*>(&w_lds[0][m][4 * g + 16]);
                D1[oc][nt] = __builtin_amdgcn_mfma_f32_16x16x32_bf16(
                    __builtin_bit_cast(short8, A0), __builtin_bit_cast(short8, B0),
                    D1[oc][nt], 0, 0, 0);
                D1[oc][nt] = __builtin_amdgcn_mfma_f32_16x16x32_bf16(
                    __builtin_bit_cast(short8, A1), __builtin_bit_cast(short8, B1),
                    D1[oc][nt], 0, 0, 0);
            }
        }

        // ---- acc = x * g  -> overwrite s_buf (own column slab only) ----
        #pragma unroll
        for (int nt = 0; nt < 2; ++nt) {
            const int n  = ln + 16 * (2 * w + nt);
            const int cg = bCL + col0 + n;
            #pragma unroll
            for (int oc = 0; oc < 4; ++oc) {
                const int m0 = 16 * oc + 4 * g;
                float av[4];
                #pragma unroll
                for (int j = 0; j < 4; ++j)
                    av[j] = x[cg + (m0 + j) * Lv] * D1[oc][nt][j];
                s_buf[(8 * oc + 2 * g) * SSTRIDE + n]     = pack2bf(av[0], av[1]);
                s_buf[(8 * oc + 2 * g + 1) * SSTRIDE + n] = pack2bf(av[2], av[3]);
            }
        }

        // ---- GEMM2: u = Wf . acc + fuse_b ----
        f32x4 D2[4][2];
        #pragma unroll
        for (int oc = 0; oc < 4; ++oc) { D2[oc][0] = fbi[oc]; D2[oc][1] = fbi[oc]; }
        #pragma unroll
        for (int nt = 0; nt < 2; ++nt) {
            const int n = ln + 16 * (2 * w + nt);
            uint4 B0, B1;
            B0.x = s_buf[(4 * g + 0) * SSTRIDE + n];  B0.y = s_buf[(4 * g + 1) * SSTRIDE + n];
            B0.z = s_buf[(4 * g + 2) * SSTRIDE + n];  B0.w = s_buf[(4 * g + 3) * SSTRIDE + n];
            B1.x = s_buf[(4 * g + 16) * SSTRIDE + n]; B1.y = s_buf[(4 * g + 17) * SSTRIDE + n];
            B1.z = s_buf[(4 * g + 18) * SSTRIDE + n]; B1.w = s_buf[(4 * g + 19) * SSTRIDE + n];
            #pragma unroll
            for (int oc = 0; oc < 4; ++oc) {
                const int m = ln + 16 * oc;
                const uint4 A0 = *reinterpret_cast<const uint4*>(&w_lds[1][m][4 * g]);
                const uint4 A1 = *reinterpret_cast<const uint4*>(&w_lds[1][m][4 * g + 16]);
                D2[oc][nt] = __builtin_amdgcn_mfma_f32_16x16x32_bf16(
                    __builtin_bit_cast(short8, A0), __builtin_bit_cast(short8, B0),
                    D2[oc][nt], 0, 0, 0);
                D2[oc][nt] = __builtin_amdgcn_mfma_f32_16x16x32_bf16(
                    __builtin_bit_cast(short8, A1), __builtin_bit_cast(short8, B1),
                    D2[oc][nt], 0, 0, 0);
            }
        }

        // ---- epilogue via LDS re-layout: +resid, ReLU, stats, coalesced ----
        float* uf = reinterpret_cast<float*>(s_buf);
        #pragma unroll 1
        for (int ch = 0; ch < 2; ++ch) {
            // fragments -> u tile (rows m&31, own col slab: no barrier needed)
            #pragma unroll
            for (int oc = 2 * ch; oc < 2 * ch + 2; ++oc)
                #pragma unroll
                for (int nt = 0; nt < 2; ++nt) {
                    const int n = ln + 16 * (2 * w + nt);
                    #pragma unroll
                    for (int j = 0; j < 4; ++j) {
                        const int mr = (16 * oc + 4 * g + j) & 31;
                        uf[mr * SSTRIDE + n] = D2[oc][nt][j];
                    }
                }
            // prefetch chunk-1 resid while chunk-0 finishes
            float4 rp1[4];
            if (ch == 0) {
                const int gb1 = bCL + (32 + rowin) * Lv + col0;
                #pragma unroll
                for (int i = 0; i < 4; ++i)
                    rp1[i] = *reinterpret_cast<const float4*>(&resid[gb1 + 4 * (cl + 8 * i)]);
            }
            __syncthreads();
            const int m  = 32 * ch + rowin;
            const int gb = bCL + m * Lv + col0;
            #pragma unroll
            for (int i = 0; i < 4; ++i) {
                const int c = 4 * (cl + 8 * i);
                float4 v = *reinterpret_cast<const float4*>(&uf[rowin * SSTRIDE + c]);
                const float4 r = (ch == 0) ? rp0[i] : rp0[i];  // placeholder, fixed below
                float4 rr = rp0[i];
                if (ch == 1) rr = rp1[i];
                (void)r;
                v.x = fmaxf(v.x + rr.x, 0.0f);
                v.y = fmaxf(v.y + rr.y, 0.0f);
                v.z = fmaxf(v.z + rr.z, 0.0f);
                v.w = fmaxf(v.w + rr.w, 0.0f);
                *reinterpret_cast<float4*>(&out[gb + c]) = v;
                lsum += (v.x + v.y) + (v.z + v.w);
                lsq = fmaf(v.x, v.x, lsq);
                lsq = fmaf(v.y, v.y, lsq);
                lsq = fmaf(v.z, v.z, lsq);
                lsq = fmaf(v.w, v.w, lsq);
            }
            if (ch == 0) {
                #pragma unroll
                for (int i = 0; i < 4; ++i) rp0[i] = rp1[i];   // carry to ch=1
            }
            __syncthreads();   // tile reads done before reuse (next chunk/half)
        }
    }

    // ---- deterministic block reduction -> per-block partials ----
    r1[tid] = lsum; r2[tid] = lsq;
    __syncthreads();
    #pragma unroll
    for (int st = TPB / 2; st > 0; st >>= 1) {
        if (tid < st) { r1[tid] += r1[tid + st]; r2[tid] += r2[tid + st]; }
        __syncthreads();
    }
    if (tid == 0) {
        partials[2 * blockIdx.x]     = r1[0];
        partials[2 * blockIdx.x + 1] = r2[0];
    }
}

// ---------------------------------------------------------------------------
// Pass 2: reduce 256 partials per batch -> per-(b,c) scale/bias.
// ---------------------------------------------------------------------------
__global__ __launch_bounds__(256)
void pass2(const float* __restrict__ partials, const float* __restrict__ gn_w,
           const float* __restrict__ gn_b, float* __restrict__ sb)
{
    __shared__ float r1[256], r2[256];
    __shared__ float mean_s, rs_s;
    const int b = blockIdx.x, tid = threadIdx.x;
    r1[tid] = partials[2 * (b * 256 + tid)];
    r2[tid] = partials[2 * (b * 256 + tid) + 1];
    __syncthreads();
    #pragma unroll
    for (int st = 128; st > 0; st >>= 1) {
        if (tid < st) { r1[tid] += r1[tid + st]; r2[tid] += r2[tid + st]; }
        __syncthreads();
    }
    if (tid == 0) {
        const float n = (float)Cv * (float)Lv;
        const float mean = r1[0] / n;
        const float var  = r2[0] / n - mean * mean;
        mean_s = mean;
        rs_s   = rsqrtf(var + 1e-5f);
    }
    __syncthreads();
    if (tid < Cv) {
        const float sc = gn_w[tid] * rs_s;
        sb[b * Cv + tid]           = sc;
        sb[Bv * Cv + b * Cv + tid] = fmaf(-mean_s, sc, gn_b[tid]);
    }
}

// ---------------------------------------------------------------------------
// Pass 3: in-place GroupNorm affine on d_out (float4 vectorized).
// ---------------------------------------------------------------------------
__global__ __launch_bounds__(256)
void pass3(float* __restrict__ out, const float* __restrict__ sb)
{
    const int total4 = (Bv * Cv * Lv) / 4;   // 8388608
    for (int i = blockIdx.x * blockDim.x + threadIdx.x; i < total4;
         i += gridDim.x * blockDim.x) {
        const int row = i >> 14;            // / (L/4): row = b*64 + c
        const float sc = sb[row];
        const float bi = sb[Bv * Cv + row];
        float4 v = reinterpret_cast<float4*>(out)[i];
        v.x = fmaf(v.x, sc, bi);
        v.y = fmaf(v.y, sc, bi);
        v.z = fmaf(v.z, sc, bi);
        v.w = fmaf(v.w, sc, bi);
        reinterpret_cast<float4*>(out)[i] = v;
    }
}

extern "C" void kernel_launch(void* const* d_in, const int* in_sizes, int n_in,
                              void* d_out, int out_size, void* d_ws, size_t ws_size,
                              hipStream_t stream)
{
    const float* x      = (const float*)d_in[0];
    const float* inj0   = (const float*)d_in[1];
    const float* inj1   = (const float*)d_in[2];
    const float* resid  = (const float*)d_in[3];
    const float* gate_w = (const float*)d_in[4];
    const float* gate_b = (const float*)d_in[5];
    const float* fuse_w = (const float*)d_in[6];
    const float* fuse_b = (const float*)d_in[7];
    const float* gn_w   = (const float*)d_in[8];
    const float* gn_b   = (const float*)d_in[9];

    float* out      = (float*)d_out;
    float* ws       = (float*)d_ws;
    float* partials = ws;                 // 2 * 2048 floats = 16 KiB
    float* sb       = ws + 2 * GRID1;     // 2 * 512 floats  =  4 KiB

    hipLaunchKernelGGL(pass1, dim3(GRID1), dim3(TPB), 0, stream,
                       x, inj0, inj1, resid, gate_w, gate_b, fuse_w, fuse_b,
                       out, partials);
    hipLaunchKernelGGL(pass2, dim3(Bv), dim3(256), 0, stream,
                       partials, gn_w, gn_b, sb);
    hipLaunchKernelGGL(pass3, dim3(2048), dim3(256), 0, stream, out, sb);
}

// Round 8
// 215.863 us; speedup vs baseline: 1.6080x; 1.1621x over previous
//
#include <hip/hip_runtime.h>
#include <stdint.h>

#define Bv 8
#define Cv 64
#define Lv 65536
#define TPB 256
#define LOCS_PER_BLK 256              // 2 halves x 128
#define HALF_LOCS 128
#define BLKS_PER_B (Lv / LOCS_PER_BLK) // 256
#define GRID1 (Bv * BLKS_PER_B)        // 2048

// workspace: partials 2*2048 floats (16 KiB) + sb 1024 floats (4 KiB) = 20 KiB
// (proven footprint; do not grow — R3's 36 KiB overflowed ws)

typedef __attribute__((ext_vector_type(8))) short short8;
typedef __attribute__((ext_vector_type(4))) float f32x4;

#define SSTRIDE 132   // dwords per row of s_buf; keeps float4 rows 16B-aligned

__device__ __forceinline__ uint16_t f2bf(float f) {
    uint32_t u = __float_as_uint(f);
    uint32_t r = u + 0x7FFFu + ((u >> 16) & 1u);   // round-to-nearest-even
    return (uint16_t)(r >> 16);
}
__device__ __forceinline__ uint32_t pack2bf(float lo, float hi) {
    return (uint32_t)f2bf(lo) | ((uint32_t)f2bf(hi) << 16);
}

// ---------------------------------------------------------------------------
// Pass 1 (MFMA): out = relu(Wf·(x ⊙ (Wg·s + 2bg)) + bf + resid), s=i0+i1+2x
// Register budget is the binding constraint: 128/wave total at 4 waves/SIMD,
// 64 go to MFMA accumulators. C-init constants live in LDS (not 32 pinned
// VGPRs); A-fragment reads hoisted out of the nt loop.
// ---------------------------------------------------------------------------
__global__ void pass1(const float* __restrict__ x, const float* __restrict__ inj0,
                      const float* __restrict__ inj1, const float* __restrict__ resid,
                      const float* __restrict__ gate_w, const float* __restrict__ gate_b,
                      const float* __restrict__ fuse_w, const float* __restrict__ fuse_b,
                      float* __restrict__ out, float* __restrict__ partials)
{
    __shared__ uint32_t s_buf[32 * SSTRIDE];
    __shared__ uint32_t w_lds[2][64][36];
    __shared__ float cinit[2][64];          // [0]=2*gate_b, [1]=fuse_b
    __shared__ float r1[TPB], r2[TPB];

    const int tid  = threadIdx.x;
    const int lane = tid & 63;
    const int w    = tid >> 6;     // wave 0..3
    const int g    = lane >> 4;    // k-group 0..3
    const int ln   = lane & 15;    // 0..15

    const int b    = blockIdx.x >> 8;
    const int lb   = blockIdx.x & 255;
    const int bCL  = b * (Cv * Lv);

    // ---- stage weights + C-init constants (once) ----
    {
        const int m  = tid >> 2;
        const int k0 = (tid & 3) << 4;
        const float4* wg4 = reinterpret_cast<const float4*>(gate_w + m * 64 + k0);
        const float4* wf4 = reinterpret_cast<const float4*>(fuse_w + m * 64 + k0);
        uint32_t* dg = &w_lds[0][m][k0 >> 1];
        uint32_t* df = &w_lds[1][m][k0 >> 1];
        #pragma unroll
        for (int q = 0; q < 4; ++q) {
            const float4 vg = wg4[q];
            dg[2 * q]     = pack2bf(vg.x, vg.y);
            dg[2 * q + 1] = pack2bf(vg.z, vg.w);
            const float4 vf = wf4[q];
            df[2 * q]     = pack2bf(vf.x, vf.y);
            df[2 * q + 1] = pack2bf(vf.z, vf.w);
        }
        if (tid < 64) {
            cinit[0][tid] = 2.0f * gate_b[tid];
            cinit[1][tid] = fuse_b[tid];
        }
    }

    const int rowin = tid >> 3;          // 0..31: epilogue LDS row
    const int cl    = tid & 7;           // 8 lanes x float4 = 128B per row

    float lsum = 0.0f, lsq = 0.0f;

    #pragma unroll 1
    for (int h = 0; h < 2; ++h) {
        const int col0 = lb * LOCS_PER_BLK + h * HALF_LOCS;

        // ---- phase A: stage s = i0 + i1 + 2x as bf16 pairs (float4 loads) --
        {
            const int kp  = tid >> 3;              // channel pair 0..31
            const int cq0 = tid & 7;               // col-quad base
            const int rA  = bCL + (2 * kp) * Lv + col0;
            const int rB  = rA + Lv;
            #pragma unroll
            for (int u = 0; u < 4; ++u) {
                const int c = 4 * (cq0 + 8 * u);   // col offset (floats)
                const float4 xA = *reinterpret_cast<const float4*>(x    + rA + c);
                const float4 aA = *reinterpret_cast<const float4*>(inj0 + rA + c);
                const float4 bA = *reinterpret_cast<const float4*>(inj1 + rA + c);
                const float4 xB = *reinterpret_cast<const float4*>(x    + rB + c);
                const float4 aB = *reinterpret_cast<const float4*>(inj0 + rB + c);
                const float4 bB = *reinterpret_cast<const float4*>(inj1 + rB + c);
                uint4 dw;
                dw.x = pack2bf(aA.x + bA.x + 2.0f * xA.x, aB.x + bB.x + 2.0f * xB.x);
                dw.y = pack2bf(aA.y + bA.y + 2.0f * xA.y, aB.y + bB.y + 2.0f * xB.y);
                dw.z = pack2bf(aA.z + bA.z + 2.0f * xA.z, aB.z + bB.z + 2.0f * xB.z);
                dw.w = pack2bf(aA.w + bA.w + 2.0f * xA.w, aB.w + bB.w + 2.0f * xB.w);
                *reinterpret_cast<uint4*>(&s_buf[kp * SSTRIDE + c]) = dw;
            }
        }
        __syncthreads();

        // ---- prefetch resid for epilogue chunk 0 (hides under GEMMs) ----
        float4 rp0[4];
        {
            const int gb0 = bCL + rowin * Lv + col0;
            #pragma unroll
            for (int i = 0; i < 4; ++i)
                rp0[i] = *reinterpret_cast<const float4*>(&resid[gb0 + 4 * (cl + 8 * i)]);
        }

        // ---- GEMM1: g = Wg . s + 2*gate_b ----
        f32x4 D1[4][2];
        #pragma unroll
        for (int oc = 0; oc < 4; ++oc) {
            const float4 cb = *reinterpret_cast<const float4*>(&cinit[0][16 * oc + 4 * g]);
            D1[oc][0][0] = cb.x; D1[oc][0][1] = cb.y;
            D1[oc][0][2] = cb.z; D1[oc][0][3] = cb.w;
            D1[oc][1] = D1[oc][0];
        }
        {
            uint4 Bf[2][2];   // [nt][khalf]
            #pragma unroll
            for (int nt = 0; nt < 2; ++nt) {
                const int n = ln + 16 * (2 * w + nt);
                Bf[nt][0].x = s_buf[(4 * g + 0) * SSTRIDE + n];
                Bf[nt][0].y = s_buf[(4 * g + 1) * SSTRIDE + n];
                Bf[nt][0].z = s_buf[(4 * g + 2) * SSTRIDE + n];
                Bf[nt][0].w = s_buf[(4 * g + 3) * SSTRIDE + n];
                Bf[nt][1].x = s_buf[(4 * g + 16) * SSTRIDE + n];
                Bf[nt][1].y = s_buf[(4 * g + 17) * SSTRIDE + n];
                Bf[nt][1].z = s_buf[(4 * g + 18) * SSTRIDE + n];
                Bf[nt][1].w = s_buf[(4 * g + 19) * SSTRIDE + n];
            }
            #pragma unroll
            for (int oc = 0; oc < 4; ++oc) {
                const int m = ln + 16 * oc;
                const uint4 A0 = *reinterpret_cast<const uint4*>(&w_lds[0][m][4 * g]);
                const uint4 A1 = *reinterpret_cast<const uint4*>(&w_lds[0][m][4 * g + 16]);
                #pragma unroll
                for (int nt = 0; nt < 2; ++nt) {
                    D1[oc][nt] = __builtin_amdgcn_mfma_f32_16x16x32_bf16(
                        __builtin_bit_cast(short8, A0), __builtin_bit_cast(short8, Bf[nt][0]),
                        D1[oc][nt], 0, 0, 0);
                    D1[oc][nt] = __builtin_amdgcn_mfma_f32_16x16x32_bf16(
                        __builtin_bit_cast(short8, A1), __builtin_bit_cast(short8, Bf[nt][1]),
                        D1[oc][nt], 0, 0, 0);
                }
            }
        }

        // ---- acc = x * g  -> overwrite s_buf (own column slab only) ----
        #pragma unroll
        for (int nt = 0; nt < 2; ++nt) {
            const int n  = ln + 16 * (2 * w + nt);
            const int cg = bCL + col0 + n;
            #pragma unroll
            for (int oc = 0; oc < 4; ++oc) {
                const int m0 = 16 * oc + 4 * g;
                float av[4];
                #pragma unroll
                for (int j = 0; j < 4; ++j)
                    av[j] = x[cg + (m0 + j) * Lv] * D1[oc][nt][j];
                s_buf[(8 * oc + 2 * g) * SSTRIDE + n]     = pack2bf(av[0], av[1]);
                s_buf[(8 * oc + 2 * g + 1) * SSTRIDE + n] = pack2bf(av[2], av[3]);
            }
        }

        // ---- GEMM2: u = Wf . acc + fuse_b ----
        f32x4 D2[4][2];
        #pragma unroll
        for (int oc = 0; oc < 4; ++oc) {
            const float4 cb = *reinterpret_cast<const float4*>(&cinit[1][16 * oc + 4 * g]);
            D2[oc][0][0] = cb.x; D2[oc][0][1] = cb.y;
            D2[oc][0][2] = cb.z; D2[oc][0][3] = cb.w;
            D2[oc][1] = D2[oc][0];
        }
        {
            uint4 Bf[2][2];
            #pragma unroll
            for (int nt = 0; nt < 2; ++nt) {
                const int n = ln + 16 * (2 * w + nt);
                Bf[nt][0].x = s_buf[(4 * g + 0) * SSTRIDE + n];
                Bf[nt][0].y = s_buf[(4 * g + 1) * SSTRIDE + n];
                Bf[nt][0].z = s_buf[(4 * g + 2) * SSTRIDE + n];
                Bf[nt][0].w = s_buf[(4 * g + 3) * SSTRIDE + n];
                Bf[nt][1].x = s_buf[(4 * g + 16) * SSTRIDE + n];
                Bf[nt][1].y = s_buf[(4 * g + 17) * SSTRIDE + n];
                Bf[nt][1].z = s_buf[(4 * g + 18) * SSTRIDE + n];
                Bf[nt][1].w = s_buf[(4 * g + 19) * SSTRIDE + n];
            }
            #pragma unroll
            for (int oc = 0; oc < 4; ++oc) {
                const int m = ln + 16 * oc;
                const uint4 A0 = *reinterpret_cast<const uint4*>(&w_lds[1][m][4 * g]);
                const uint4 A1 = *reinterpret_cast<const uint4*>(&w_lds[1][m][4 * g + 16]);
                #pragma unroll
                for (int nt = 0; nt < 2; ++nt) {
                    D2[oc][nt] = __builtin_amdgcn_mfma_f32_16x16x32_bf16(
                        __builtin_bit_cast(short8, A0), __builtin_bit_cast(short8, Bf[nt][0]),
                        D2[oc][nt], 0, 0, 0);
                    D2[oc][nt] = __builtin_amdgcn_mfma_f32_16x16x32_bf16(
                        __builtin_bit_cast(short8, A1), __builtin_bit_cast(short8, Bf[nt][1]),
                        D2[oc][nt], 0, 0, 0);
                }
            }
        }

        // ---- epilogue via LDS re-layout: +resid, ReLU, stats, coalesced ----
        float* uf = reinterpret_cast<float*>(s_buf);
        #pragma unroll 1
        for (int ch = 0; ch < 2; ++ch) {
            // fragments -> u tile (rows m&31, own col slab: no barrier needed)
            #pragma unroll
            for (int oc = 2 * ch; oc < 2 * ch + 2; ++oc)
                #pragma unroll
                for (int nt = 0; nt < 2; ++nt) {
                    const int n = ln + 16 * (2 * w + nt);
                    #pragma unroll
                    for (int j = 0; j < 4; ++j) {
                        const int mr = (16 * oc + 4 * g + j) & 31;
                        uf[mr * SSTRIDE + n] = D2[oc][nt][j];
                    }
                }
            // prefetch chunk-1 resid while chunk-0 tile settles
            float4 rp1[4];
            if (ch == 0) {
                const int gb1 = bCL + (32 + rowin) * Lv + col0;
                #pragma unroll
                for (int i = 0; i < 4; ++i)
                    rp1[i] = *reinterpret_cast<const float4*>(&resid[gb1 + 4 * (cl + 8 * i)]);
            }
            __syncthreads();
            const int m  = 32 * ch + rowin;
            const int gb = bCL + m * Lv + col0;
            #pragma unroll
            for (int i = 0; i < 4; ++i) {
                const int c = 4 * (cl + 8 * i);
                float4 v = *reinterpret_cast<const float4*>(&uf[rowin * SSTRIDE + c]);
                const float4 rr = rp0[i];
                v.x = fmaxf(v.x + rr.x, 0.0f);
                v.y = fmaxf(v.y + rr.y, 0.0f);
                v.z = fmaxf(v.z + rr.z, 0.0f);
                v.w = fmaxf(v.w + rr.w, 0.0f);
                *reinterpret_cast<float4*>(&out[gb + c]) = v;
                lsum += (v.x + v.y) + (v.z + v.w);
                lsq = fmaf(v.x, v.x, lsq);
                lsq = fmaf(v.y, v.y, lsq);
                lsq = fmaf(v.z, v.z, lsq);
                lsq = fmaf(v.w, v.w, lsq);
            }
            if (ch == 0) {
                #pragma unroll
                for (int i = 0; i < 4; ++i) rp0[i] = rp1[i];   // carry to ch=1
            }
            __syncthreads();   // tile reads done before reuse (next chunk/half)
        }
    }

    // ---- deterministic block reduction -> per-block partials ----
    r1[tid] = lsum; r2[tid] = lsq;
    __syncthreads();
    #pragma unroll
    for (int st = TPB / 2; st > 0; st >>= 1) {
        if (tid < st) { r1[tid] += r1[tid + st]; r2[tid] += r2[tid + st]; }
        __syncthreads();
    }
    if (tid == 0) {
        partials[2 * blockIdx.x]     = r1[0];
        partials[2 * blockIdx.x + 1] = r2[0];
    }
}

// ---------------------------------------------------------------------------
// Pass 2: reduce 256 partials per batch -> per-(b,c) scale/bias.
// ---------------------------------------------------------------------------
__global__ __launch_bounds__(256)
void pass2(const float* __restrict__ partials, const float* __restrict__ gn_w,
           const float* __restrict__ gn_b, float* __restrict__ sb)
{
    __shared__ float r1[256], r2[256];
    __shared__ float mean_s, rs_s;
    const int b = blockIdx.x, tid = threadIdx.x;
    r1[tid] = partials[2 * (b * 256 + tid)];
    r2[tid] = partials[2 * (b * 256 + tid) + 1];
    __syncthreads();
    #pragma unroll
    for (int st = 128; st > 0; st >>= 1) {
        if (tid < st) { r1[tid] += r1[tid + st]; r2[tid] += r2[tid + st]; }
        __syncthreads();
    }
    if (tid == 0) {
        const float n = (float)Cv * (float)Lv;
        const float mean = r1[0] / n;
        const float var  = r2[0] / n - mean * mean;
        mean_s = mean;
        rs_s   = rsqrtf(var + 1e-5f);
    }
    __syncthreads();
    if (tid < Cv) {
        const float sc = gn_w[tid] * rs_s;
        sb[b * Cv + tid]           = sc;
        sb[Bv * Cv + b * Cv + tid] = fmaf(-mean_s, sc, gn_b[tid]);
    }
}

// ---------------------------------------------------------------------------
// Pass 3: in-place GroupNorm affine on d_out (float4 vectorized).
// ---------------------------------------------------------------------------
__global__ __launch_bounds__(256)
void pass3(float* __restrict__ out, const float* __restrict__ sb)
{
    const int total4 = (Bv * Cv * Lv) / 4;   // 8388608
    for (int i = blockIdx.x * blockDim.x + threadIdx.x; i < total4;
         i += gridDim.x * blockDim.x) {
        const int row = i >> 14;            // / (L/4): row = b*64 + c
        const float sc = sb[row];
        const float bi = sb[Bv * Cv + row];
        float4 v = reinterpret_cast<float4*>(out)[i];
        v.x = fmaf(v.x, sc, bi);
        v.y = fmaf(v.y, sc, bi);
        v.z = fmaf(v.z, sc, bi);
        v.w = fmaf(v.w, sc, bi);
        reinterpret_cast<float4*>(out)[i] = v;
    }
}

extern "C" void kernel_launch(void* const* d_in, const int* in_sizes, int n_in,
                              void* d_out, int out_size, void* d_ws, size_t ws_size,
                              hipStream_t stream)
{
    const float* x      = (const float*)d_in[0];
    const float* inj0   = (const float*)d_in[1];
    const float* inj1   = (const float*)d_in[2];
    const float* resid  = (const float*)d_in[3];
    const float* gate_w = (const float*)d_in[4];
    const float* gate_b = (const float*)d_in[5];
    const float* fuse_w = (const float*)d_in[6];
    const float* fuse_b = (const float*)d_in[7];
    const float* gn_w   = (const float*)d_in[8];
    const float* gn_b   = (const float*)d_in[9];

    float* out      = (float*)d_out;
    float* ws       = (float*)d_ws;
    float* partials = ws;                 // 2 * 2048 floats = 16 KiB
    float* sb       = ws + 2 * GRID1;     // 2 * 512 floats  =  4 KiB

    hipLaunchKernelGGL(pass1, dim3(GRID1), dim3(TPB), 0, stream,
                       x, inj0, inj1, resid, gate_w, gate_b, fuse_w, fuse_b,
                       out, partials);
    hipLaunchKernelGGL(pass2, dim3(Bv), dim3(256), 0, stream,
                       partials, gn_w, gn_b, sb);
    hipLaunchKernelGGL(pass3, dim3(2048), dim3(256), 0, stream, out, sb);
}

// Round 10
// 186.624 us; speedup vs baseline: 1.8599x; 1.1567x over previous
//
#include <hip/hip_runtime.h>
#include <stdint.h>

#define Bv 8
#define Cv 64
#define Lv 65536
#define TPB 512
#define COLS 256                      // contiguous cols per block (1KB/row bursts)
#define BLKS_PER_B (Lv / COLS)        // 256
#define GRID1 (Bv * BLKS_PER_B)       // 2048

// workspace: partials 2*2048 floats (16 KiB) + sb 1024 floats (4 KiB) = 20 KiB
// (proven footprint; do not grow)

typedef __attribute__((ext_vector_type(8))) short short8;
typedef __attribute__((ext_vector_type(4))) float f32x4;

#define SSTRIDE 260   // dwords per s_buf row: 16B-aligned, 260%32=4 staggers banks

__device__ __forceinline__ uint16_t f2bf(float f) {
    uint32_t u = __float_as_uint(f);
    uint32_t r = u + 0x7FFFu + ((u >> 16) & 1u);   // round-to-nearest-even
    return (uint16_t)(r >> 16);
}
__device__ __forceinline__ uint32_t pack2bf(float lo, float hi) {
    return (uint32_t)f2bf(lo) | ((uint32_t)f2bf(hi) << 16);
}

// ---------------------------------------------------------------------------
// Pass 1 (MFMA, K-split): out = relu(Wf·(x ⊙ (Wg·s + 2bg)) + bf + resid)
// Tile 64ch x 256cols, 8 waves. s_buf holds ONE 32-ch K-half at a time
// (16 kpairs x 260 dwords); GEMM1/GEMM2 each accumulate over 2 K-halves.
// All global traffic is 1KB-per-row bursts (DRAM page locality probe —
// R8 was stuck at ~2.8 TB/s with 512B chunks).
// R10 fix vs R9: __syncthreads() after weight/cinit staging BEFORE the D1
// C-init reads cinit (R9 raced: waves 1-7 read cinit before wave 0 wrote it).
// ---------------------------------------------------------------------------
__global__ void pass1(const float* __restrict__ x, const float* __restrict__ inj0,
                      const float* __restrict__ inj1, const float* __restrict__ resid,
                      const float* __restrict__ gate_w, const float* __restrict__ gate_b,
                      const float* __restrict__ fuse_w, const float* __restrict__ fuse_b,
                      float* __restrict__ out, float* __restrict__ partials)
{
    __shared__ uint32_t s_buf[16 * SSTRIDE];       // 16.6 KB
    __shared__ uint32_t w_lds[2][64][36];          // 18.4 KB
    __shared__ float cinit[2][64];                 // [0]=2*gate_b, [1]=fuse_b
    __shared__ float r1[TPB], r2[TPB];             // 4 KB

    const int tid  = threadIdx.x;
    const int lane = tid & 63;
    const int w    = tid >> 6;     // wave 0..7
    const int g    = lane >> 4;    // k-group 0..3
    const int ln   = lane & 15;    // 0..15

    const int b    = blockIdx.x >> 8;
    const int lb   = blockIdx.x & 255;
    const int col0 = lb * COLS;
    const int bCL  = b * (Cv * Lv);

    // ---- stage weights (once): 512 units = 2 mats x 64 rows x 4 k-quads ----
    {
        const int mat = tid >> 8;              // 0=gate, 1=fuse
        const int m   = (tid >> 2) & 63;
        const int k0  = (tid & 3) << 4;
        const float* wsrc = mat ? fuse_w : gate_w;
        const float4* w4 = reinterpret_cast<const float4*>(wsrc + m * 64 + k0);
        uint32_t* dst = &w_lds[mat][m][k0 >> 1];
        #pragma unroll
        for (int q = 0; q < 4; ++q) {
            const float4 v = w4[q];
            dst[2 * q]     = pack2bf(v.x, v.y);
            dst[2 * q + 1] = pack2bf(v.z, v.w);
        }
        if (tid < 64) {
            cinit[0][tid] = 2.0f * gate_b[tid];
            cinit[1][tid] = fuse_b[tid];
        }
    }
    __syncthreads();   // cinit/w_lds visible to all waves (R9's missing barrier)

    // ---- GEMM1 (K-split): D1 = Wg . s + 2*gate_b ----
    f32x4 D1[4][2];
    #pragma unroll
    for (int oc = 0; oc < 4; ++oc) {
        const float4 cb = *reinterpret_cast<const float4*>(&cinit[0][16 * oc + 4 * g]);
        D1[oc][0][0] = cb.x; D1[oc][0][1] = cb.y;
        D1[oc][0][2] = cb.z; D1[oc][0][3] = cb.w;
        D1[oc][1] = D1[oc][0];
    }

    #pragma unroll 1
    for (int kh = 0; kh < 2; ++kh) {
        // stage s = i0+i1+2x for ch [32kh, 32kh+32) as bf16 kpairs
        #pragma unroll
        for (int uu = 0; uu < 2; ++uu) {
            const int u  = tid + uu * TPB;
            const int kp = u >> 6;               // 0..15
            const int c  = (u & 63) << 2;        // col 0..252
            const int rA = bCL + (32 * kh + 2 * kp) * Lv + col0 + c;
            const int rB = rA + Lv;
            const float4 xA = *reinterpret_cast<const float4*>(x    + rA);
            const float4 aA = *reinterpret_cast<const float4*>(inj0 + rA);
            const float4 bA = *reinterpret_cast<const float4*>(inj1 + rA);
            const float4 xB = *reinterpret_cast<const float4*>(x    + rB);
            const float4 aB = *reinterpret_cast<const float4*>(inj0 + rB);
            const float4 bB = *reinterpret_cast<const float4*>(inj1 + rB);
            uint4 dw;
            dw.x = pack2bf(aA.x + bA.x + 2.0f * xA.x, aB.x + bB.x + 2.0f * xB.x);
            dw.y = pack2bf(aA.y + bA.y + 2.0f * xA.y, aB.y + bB.y + 2.0f * xB.y);
            dw.z = pack2bf(aA.z + bA.z + 2.0f * xA.z, aB.z + bB.z + 2.0f * xB.z);
            dw.w = pack2bf(aA.w + bA.w + 2.0f * xA.w, aB.w + bB.w + 2.0f * xB.w);
            *reinterpret_cast<uint4*>(&s_buf[kp * SSTRIDE + c]) = dw;
        }
        __syncthreads();

        // partial-K MFMA (K=32): A dwords [16kh+4g .. +3]
        #pragma unroll
        for (int nt = 0; nt < 2; ++nt) {
            const int n = ln + 16 * (2 * w + nt);
            uint4 Bf;
            Bf.x = s_buf[(4 * g + 0) * SSTRIDE + n];
            Bf.y = s_buf[(4 * g + 1) * SSTRIDE + n];
            Bf.z = s_buf[(4 * g + 2) * SSTRIDE + n];
            Bf.w = s_buf[(4 * g + 3) * SSTRIDE + n];
            #pragma unroll
            for (int oc = 0; oc < 4; ++oc) {
                const int m = ln + 16 * oc;
                const uint4 A = *reinterpret_cast<const uint4*>(&w_lds[0][m][16 * kh + 4 * g]);
                D1[oc][nt] = __builtin_amdgcn_mfma_f32_16x16x32_bf16(
                    __builtin_bit_cast(short8, A), __builtin_bit_cast(short8, Bf),
                    D1[oc][nt], 0, 0, 0);
            }
        }
        __syncthreads();   // readers done before next-stage overwrite
    }

    // ---- acc = x*g  +  GEMM2 (K-split): D2 = Wf . acc + fuse_b ----
    f32x4 D2[4][2];
    #pragma unroll
    for (int oc = 0; oc < 4; ++oc) {
        const float4 cb = *reinterpret_cast<const float4*>(&cinit[1][16 * oc + 4 * g]);
        D2[oc][0][0] = cb.x; D2[oc][0][1] = cb.y;
        D2[oc][0][2] = cb.z; D2[oc][0][3] = cb.w;
        D2[oc][1] = D2[oc][0];
    }
    #pragma unroll
    for (int kh = 0; kh < 2; ++kh) {
        // acc for ch [32kh, 32kh+32): x re-read (L1/L2-hot), pack to s_buf
        #pragma unroll
        for (int nt = 0; nt < 2; ++nt) {
            const int n  = ln + 16 * (2 * w + nt);
            const int cg = bCL + col0 + n;
            #pragma unroll
            for (int oc2 = 0; oc2 < 2; ++oc2) {
                const int oc = 2 * kh + oc2;
                const int m0 = 16 * oc + 4 * g;
                float av[4];
                #pragma unroll
                for (int j = 0; j < 4; ++j)
                    av[j] = x[cg + (m0 + j) * Lv] * D1[oc][nt][j];
                s_buf[(8 * oc2 + 2 * g) * SSTRIDE + n]     = pack2bf(av[0], av[1]);
                s_buf[(8 * oc2 + 2 * g + 1) * SSTRIDE + n] = pack2bf(av[2], av[3]);
            }
        }
        __syncthreads();
        #pragma unroll
        for (int nt = 0; nt < 2; ++nt) {
            const int n = ln + 16 * (2 * w + nt);
            uint4 Bf;
            Bf.x = s_buf[(4 * g + 0) * SSTRIDE + n];
            Bf.y = s_buf[(4 * g + 1) * SSTRIDE + n];
            Bf.z = s_buf[(4 * g + 2) * SSTRIDE + n];
            Bf.w = s_buf[(4 * g + 3) * SSTRIDE + n];
            #pragma unroll
            for (int oc = 0; oc < 4; ++oc) {
                const int m = ln + 16 * oc;
                const uint4 A = *reinterpret_cast<const uint4*>(&w_lds[1][m][16 * kh + 4 * g]);
                D2[oc][nt] = __builtin_amdgcn_mfma_f32_16x16x32_bf16(
                    __builtin_bit_cast(short8, A), __builtin_bit_cast(short8, Bf),
                    D2[oc][nt], 0, 0, 0);
            }
        }
        __syncthreads();
    }

    // ---- epilogue: 4 chunks of 16 rows via LDS re-layout ----
    float lsum = 0.0f, lsq = 0.0f;
    {
        float* uf = reinterpret_cast<float*>(s_buf);
        const int rowin = tid >> 5;          // 0..15
        const int cl    = tid & 31;          // 32 threads x 2 float4 per row
        #pragma unroll
        for (int ck = 0; ck < 4; ++ck) {
            // fragment write: chunk rows = 16ck + (4g+j), oc = ck
            #pragma unroll
            for (int nt = 0; nt < 2; ++nt) {
                const int n = ln + 16 * (2 * w + nt);
                #pragma unroll
                for (int j = 0; j < 4; ++j)
                    uf[(4 * g + j) * SSTRIDE + n] = D2[ck][nt][j];
            }
            // prefetch resid for this chunk (hides under the barrier)
            const int m   = 16 * ck + rowin;
            const int gbm = bCL + m * Lv + col0;
            const float4 ra = *reinterpret_cast<const float4*>(&resid[gbm + 4 * cl]);
            const float4 rb = *reinterpret_cast<const float4*>(&resid[gbm + 4 * cl + 128]);
            __syncthreads();
            float4 va = *reinterpret_cast<const float4*>(&uf[rowin * SSTRIDE + 4 * cl]);
            float4 vb = *reinterpret_cast<const float4*>(&uf[rowin * SSTRIDE + 4 * cl + 128]);
            va.x = fmaxf(va.x + ra.x, 0.0f); va.y = fmaxf(va.y + ra.y, 0.0f);
            va.z = fmaxf(va.z + ra.z, 0.0f); va.w = fmaxf(va.w + ra.w, 0.0f);
            vb.x = fmaxf(vb.x + rb.x, 0.0f); vb.y = fmaxf(vb.y + rb.y, 0.0f);
            vb.z = fmaxf(vb.z + rb.z, 0.0f); vb.w = fmaxf(vb.w + rb.w, 0.0f);
            *reinterpret_cast<float4*>(&out[gbm + 4 * cl])       = va;
            *reinterpret_cast<float4*>(&out[gbm + 4 * cl + 128]) = vb;
            lsum += (va.x + va.y) + (va.z + va.w) + (vb.x + vb.y) + (vb.z + vb.w);
            lsq = fmaf(va.x, va.x, lsq); lsq = fmaf(va.y, va.y, lsq);
            lsq = fmaf(va.z, va.z, lsq); lsq = fmaf(va.w, va.w, lsq);
            lsq = fmaf(vb.x, vb.x, lsq); lsq = fmaf(vb.y, vb.y, lsq);
            lsq = fmaf(vb.z, vb.z, lsq); lsq = fmaf(vb.w, vb.w, lsq);
            __syncthreads();   // tile reads done before next chunk's writes
        }
    }

    // ---- deterministic block reduction -> per-block partials ----
    r1[tid] = lsum; r2[tid] = lsq;
    __syncthreads();
    #pragma unroll
    for (int st = TPB / 2; st > 0; st >>= 1) {
        if (tid < st) { r1[tid] += r1[tid + st]; r2[tid] += r2[tid + st]; }
        __syncthreads();
    }
    if (tid == 0) {
        partials[2 * blockIdx.x]     = r1[0];
        partials[2 * blockIdx.x + 1] = r2[0];
    }
}

// ---------------------------------------------------------------------------
// Pass 2: reduce 256 partials per batch -> per-(b,c) scale/bias.
// ---------------------------------------------------------------------------
__global__ __launch_bounds__(256)
void pass2(const float* __restrict__ partials, const float* __restrict__ gn_w,
           const float* __restrict__ gn_b, float* __restrict__ sb)
{
    __shared__ float r1[256], r2[256];
    __shared__ float mean_s, rs_s;
    const int b = blockIdx.x, tid = threadIdx.x;
    r1[tid] = partials[2 * (b * 256 + tid)];
    r2[tid] = partials[2 * (b * 256 + tid) + 1];
    __syncthreads();
    #pragma unroll
    for (int st = 128; st > 0; st >>= 1) {
        if (tid < st) { r1[tid] += r1[tid + st]; r2[tid] += r2[tid + st]; }
        __syncthreads();
    }
    if (tid == 0) {
        const float n = (float)Cv * (float)Lv;
        const float mean = r1[0] / n;
        const float var  = r2[0] / n - mean * mean;
        mean_s = mean;
        rs_s   = rsqrtf(var + 1e-5f);
    }
    __syncthreads();
    if (tid < Cv) {
        const float sc = gn_w[tid] * rs_s;
        sb[b * Cv + tid]           = sc;
        sb[Bv * Cv + b * Cv + tid] = fmaf(-mean_s, sc, gn_b[tid]);
    }
}

// ---------------------------------------------------------------------------
// Pass 3: in-place GroupNorm affine on d_out (float4 vectorized).
// ---------------------------------------------------------------------------
__global__ __launch_bounds__(256)
void pass3(float* __restrict__ out, const float* __restrict__ sb)
{
    const int total4 = (Bv * Cv * Lv) / 4;   // 8388608
    for (int i = blockIdx.x * blockDim.x + threadIdx.x; i < total4;
         i += gridDim.x * blockDim.x) {
        const int row = i >> 14;            // / (L/4): row = b*64 + c
        const float sc = sb[row];
        const float bi = sb[Bv * Cv + row];
        float4 v = reinterpret_cast<float4*>(out)[i];
        v.x = fmaf(v.x, sc, bi);
        v.y = fmaf(v.y, sc, bi);
        v.z = fmaf(v.z, sc, bi);
        v.w = fmaf(v.w, sc, bi);
        reinterpret_cast<float4*>(out)[i] = v;
    }
}

extern "C" void kernel_launch(void* const* d_in, const int* in_sizes, int n_in,
                              void* d_out, int out_size, void* d_ws, size_t ws_size,
                              hipStream_t stream)
{
    const float* x      = (const float*)d_in[0];
    const float* inj0   = (const float*)d_in[1];
    const float* inj1   = (const float*)d_in[2];
    const float* resid  = (const float*)d_in[3];
    const float* gate_w = (const float*)d_in[4];
    const float* gate_b = (const float*)d_in[5];
    const float* fuse_w = (const float*)d_in[6];
    const float* fuse_b = (const float*)d_in[7];
    const float* gn_w   = (const float*)d_in[8];
    const float* gn_b   = (const float*)d_in[9];

    float* out      = (float*)d_out;
    float* ws       = (float*)d_ws;
    float* partials = ws;                 // 2 * 2048 floats = 16 KiB
    float* sb       = ws + 2 * GRID1;     // 2 * 512 floats  =  4 KiB

    hipLaunchKernelGGL(pass1, dim3(GRID1), dim3(TPB), 0, stream,
                       x, inj0, inj1, resid, gate_w, gate_b, fuse_w, fuse_b,
                       out, partials);
    hipLaunchKernelGGL(pass2, dim3(Bv), dim3(256), 0, stream,
                       partials, gn_w, gn_b, sb);
    hipLaunchKernelGGL(pass3, dim3(2048), dim3(256), 0, stream, out, sb);
}